// Round 11
// baseline (472.277 us; speedup 1.0000x reference)
//
#include <hip/hip_runtime.h>
#include <hip/hip_bf16.h>

// Problem constants (fixed by the reference)
constexpr int M_ = 8192;      // batch
constexpr int N_ = 4096;      // out_dim
constexpr int K_ = 4096;      // in_dim
constexpr int CBOOK = 65536;
constexpr int HA = 10007, HB = 20011;
constexpr int HC3 = 3 * 40009;     // 120027
// sign hash: all constants odd => sign = +1 iff (o+i) even

// Algebra (CBOOK = 2^16, HB odd => invertible mod 2^16):
//   197*HB ≡ HA (mod 2^16)  =>  W[n][k] = P2ext[(197n+k) & 0xFFFF],
//   P2ext[u] = (u&1 ? -1 : +1) * cb[(u*HB + HC3) & 0xFFFF]   (65536-periodic)
constexpr int C0 = 197;

constexpr int BM = 256, BN = 256, BK = 32;
constexpr int NKT = K_ / BK;               // 128 K-tiles

using bf16x8 = __bf16 __attribute__((ext_vector_type(8)));
using f32x16 = float __attribute__((ext_vector_type(16)));
using u16x8  = unsigned short __attribute__((ext_vector_type(8)));

typedef __attribute__((address_space(3))) void lds_void_t;
typedef const __attribute__((address_space(1))) void gbl_void_t;

static __device__ __forceinline__ unsigned short f2bf(float f) {
    __bf16 h = (__bf16)f;   // RNE on gfx950
    return __builtin_bit_cast(unsigned short, h);
}

// ---------------------------------------------------------------------------
// prep stage 1: P2 phase-copy table  P2p[p][i] = P2ext[i+p], p<8, i<65536.
// ---------------------------------------------------------------------------
constexpr int P2N   = 8 * 65536;           // 524288 elems, 1 MiB
constexpr int P2B   = P2N / 256;           // 2048 blocks

__global__ __launch_bounds__(256) void prep_p2(const float* __restrict__ cb,
                                               unsigned short* __restrict__ P2p) {
    const int t = blockIdx.x * 256 + threadIdx.x;   // [0, 2^19)
    const int p = t >> 16;
    const int i = t & 65535;
    const int u = i + p;                            // u*HB < 2^31
    float v = cb[(u * HB + HC3) & (CBOOK - 1)];
    if (u & 1) v = -v;
    P2p[t] = f2bf(v);
}

// ---------------------------------------------------------------------------
// prep stage 2 (merged).  Both GEMM operands are written in FRAGMENT-FLAT
// order for mfma_f32_32x32x16_bf16 (operand lane l holds elem [idx = l&31]
// [k = (l>>5)*8 + j], the 32x32 analog of the verified 16x16 mapping):
//
//   blocks [0, GENB): Wf[strip][kt][slot]x8, slot = ((q*2+nt)*2+s)*64 + l:
//     n = strip*256 + q*64 + nt*32 + (l&31), k = kt*32 + s*16 + (l>>5)*8
//     value via one aligned 16B P2p load (u0 = (197n+k)&0xFFFF).
//   blocks [GENB, GENB+CONVB): xb[band][kt][slot]x8 (bf16 from x),
//     slot = ((h*4+mt)*2+s)*64 + l:
//     row = band*256 + h*128 + mt*32 + (l&31), k = kt*32 + s*16 + (l>>5)*8
//     (input reads: lanes l, l+32 cover one aligned 64B row segment -> full
//      line utilization, same 2M txns as plain conversion)
// ---------------------------------------------------------------------------
constexpr int GENB  = N_ * K_ / 8 / 256;   // 8192
constexpr int CONVB = M_ * K_ / 8 / 256;   // 16384

__global__ __launch_bounds__(256) void prep_main(const float* __restrict__ x,
                                                 const unsigned short* __restrict__ P2p,
                                                 unsigned short* __restrict__ Wf,
                                                 unsigned short* __restrict__ xb) {
    const int b = blockIdx.x;
    if (b < GENB) {
        const int t    = b * 256 + threadIdx.x;   // [0, 2^21) 16B slots
        const int slot = t & 1023;
        const int kt   = (t >> 10) & 127;
        const int strip = t >> 17;
        const int l  = slot & 63;
        const int s  = (slot >> 6) & 1;
        const int nt = (slot >> 7) & 1;
        const int q  = (slot >> 8) & 3;
        const int n  = (strip << 8) + (q << 6) + (nt << 5) + (l & 31);
        const int k0 = (kt << 5) + (s << 4) + ((l >> 5) << 3);
        const int u0 = (C0 * n + k0) & (CBOOK - 1);
        const u16x8 w = *reinterpret_cast<const u16x8*>(
            P2p + ((u0 & 7) << 16) + (u0 & 65528));     // one aligned 16B load
        *reinterpret_cast<u16x8*>(&Wf[(size_t)t * 8]) = w;   // coalesced
    } else {
        const int t    = (b - GENB) * 256 + threadIdx.x;  // [0, 2^22)
        const int slot = t & 1023;
        const int kt   = (t >> 10) & 127;
        const int band = t >> 17;
        const int l  = slot & 63;
        const int s  = (slot >> 6) & 1;
        const int mt = (slot >> 7) & 3;
        const int h  = (slot >> 9) & 1;
        const int row = (band << 8) + (h << 7) + (mt << 5) + (l & 31);
        const int k   = (kt << 5) + (s << 4) + ((l >> 5) << 3);
        const float4* p = reinterpret_cast<const float4*>(
            x + (size_t)row * K_ + k);
        const float4 a = p[0], c = p[1];
        u16x8 out;
        out[0] = f2bf(a.x); out[1] = f2bf(a.y); out[2] = f2bf(a.z); out[3] = f2bf(a.w);
        out[4] = f2bf(c.x); out[5] = f2bf(c.y); out[6] = f2bf(c.z); out[7] = f2bf(c.w);
        *reinterpret_cast<u16x8*>(&xb[(size_t)t * 8]) = out;   // coalesced
    }
}

// ---------------------------------------------------------------------------
// GEMM: C[M][N] = A[M][K] * W[N][K]^T + bias
// 256x256 tile, BK=32, 512 threads (8 waves 2Mx4N, wave tile 128x64).
// R6's proven schedule (4-deep ring 128 KB, 1 barrier/window, vmcnt(4) cert,
// afr reloads at register-death points) ported to mfma_f32_32x32x16_bf16:
//   - MFMA wall 1242 -> 1033 cyc/window (m119: 2495 vs 2176 TF), 16 MFMA
//     instead of 64 per window.
//   - Both operands staged from FRAGMENT-FLAT images (we generate them), so
//     global_load_lds is linear on both sides and every ds_read is
//     lane-linear 16B -> conflict-free, zero swizzle VALU.
//   - Cluster: kstep 0 {8 MFMA + 4 afr[0] reloads + 2 bfr[0] reloads (dead
//     after kstep 0)}, kstep 1 {8 MFMA + 4 afr[1] reloads}, 2-read bfr[1]
//     tail whose first use is after next window's kstep 0 (>=256 cyc slack).
// Cert ledger (= R6): at open(kt) outstanding stages are {kt+1, kt+2};
// vmcnt(4) certifies STAGE(kt+1) -> cluster(kt)'s reloads of slot (kt+1)&3
// are safe.  Slot overwrite (STAGE(kt+3)) is barrier-separated from its
// last reader exactly as in R6.
// ---------------------------------------------------------------------------
__global__ __launch_bounds__(512, 2) void gemm_kernel(
        const unsigned short* __restrict__ A,    // xb fragment-flat
        const unsigned short* __restrict__ Wf,   // W fragment-flat
        const float* __restrict__ bias,
        float* __restrict__ C) {
    __shared__ __align__(16) unsigned short sm[4 * 8192 * 2];  // 128 KB
    unsigned short* As = sm;                 // [4][8192]
    unsigned short* Bs = sm + 4 * 8192;      // [4][8192]

    const int tid  = threadIdx.x;
    const int lane = tid & 63;
    const int w    = tid >> 6;          // wave 0..7
    const int wm   = w >> 2;            // 0..1 -> rows wm*128
    const int wn   = w & 3;             // 0..3 -> cols wn*64
    const int m0 = blockIdx.y * BM;
    const int n0 = blockIdx.x * BN;
    const int l31 = lane & 31;
    const int lhi = lane >> 5;

    // fragment-flat sources (per-thread 16B slots, fully linear)
    const unsigned short* xbBand =
        A + (size_t)blockIdx.y * (NKT * 8192) + tid * 8;
    const unsigned short* wfStrip =
        Wf + (size_t)blockIdx.x * (NKT * 8192) + tid * 8;
    // lane-linear ds-read bases (conflict-free by construction)
    const unsigned short* aRd = As + wm * 4096 + lane * 8;
    const unsigned short* bRd = Bs + wn * 2048 + lane * 8;

    f32x16 acc[4][2] = {};              // wave tile 128x64 (128 AGPRs)
    bf16x8 afr[2][4], bfr[2][2];        // [kstep][mt/nt]

    // stage K-tile kt into ring slot bs (4 vmem loads per wave)
    auto STAGE = [&](int kt, int bs) {
#pragma unroll
        for (int r = 0; r < 2; ++r) {
            __builtin_amdgcn_global_load_lds(
                (gbl_void_t*)(xbBand + (size_t)kt * 8192 + r * 4096),
                (lds_void_t*)(As + bs * 8192 + (r * 512 + w * 64) * 8), 16, 0, 0);
            __builtin_amdgcn_global_load_lds(
                (gbl_void_t*)(wfStrip + (size_t)kt * 8192 + r * 4096),
                (lds_void_t*)(Bs + bs * 8192 + (r * 512 + w * 64) * 8), 16, 0, 0);
        }
    };

    STAGE(0, 0); STAGE(1, 1); STAGE(2, 2);
    asm volatile("s_waitcnt vmcnt(0)" ::: "memory");   // prologue full cert
    __builtin_amdgcn_s_barrier();
    // preload tile 0 fragments (slot 0)
#pragma unroll
    for (int s = 0; s < 2; ++s) {
#pragma unroll
        for (int mt = 0; mt < 4; ++mt)
            afr[s][mt] = *reinterpret_cast<const bf16x8*>(aRd + (mt * 2 + s) * 512);
#pragma unroll
        for (int nt = 0; nt < 2; ++nt)
            bfr[s][nt] = *reinterpret_cast<const bf16x8*>(bRd + (nt * 2 + s) * 512);
    }

    for (int kt0 = 0; kt0 < NKT; kt0 += 4) {
#pragma unroll
        for (int s4 = 0; s4 < 4; ++s4) {
            const int kt = kt0 + s4;
            // certify stage(kt+1) landed; keep stage(kt+2) (4 loads) in flight
            if (kt + 2 < NKT)      asm volatile("s_waitcnt vmcnt(4)" ::: "memory");
            else if (kt + 1 < NKT) asm volatile("s_waitcnt vmcnt(0)" ::: "memory");
            __builtin_amdgcn_s_barrier();            // open window kt

            if (kt + 3 < NKT) STAGE(kt + 3, (s4 + 3) & 3);

            const int rs = ((s4 + 1) & 3) * 8192;    // reload slot (imm offs)
            __builtin_amdgcn_s_setprio(1);
            // ---- kstep 0 ----
#pragma unroll
            for (int mt = 0; mt < 4; ++mt) {
                acc[mt][0] = __builtin_amdgcn_mfma_f32_32x32x16_bf16(
                    afr[0][mt], bfr[0][0], acc[mt][0], 0, 0, 0);
                acc[mt][1] = __builtin_amdgcn_mfma_f32_32x32x16_bf16(
                    afr[0][mt], bfr[0][1], acc[mt][1], 0, 0, 0);
                // afr[0][mt] dead: reload for window kt+1 (slot certified)
                afr[0][mt] = *reinterpret_cast<const bf16x8*>(
                    aRd + rs + (mt * 2 + 0) * 512);
            }
#pragma unroll
            for (int nt = 0; nt < 2; ++nt)   // bfr[0] dead after kstep 0
                bfr[0][nt] = *reinterpret_cast<const bf16x8*>(
                    bRd + rs + (nt * 2 + 0) * 512);
            // ---- kstep 1 ----
#pragma unroll
            for (int mt = 0; mt < 4; ++mt) {
                acc[mt][0] = __builtin_amdgcn_mfma_f32_32x32x16_bf16(
                    afr[1][mt], bfr[1][0], acc[mt][0], 0, 0, 0);
                acc[mt][1] = __builtin_amdgcn_mfma_f32_32x32x16_bf16(
                    afr[1][mt], bfr[1][1], acc[mt][1], 0, 0, 0);
                afr[1][mt] = *reinterpret_cast<const bf16x8*>(
                    aRd + rs + (mt * 2 + 1) * 512);
            }
#pragma unroll
            for (int nt = 0; nt < 2; ++nt)   // 2-read tail; first use is
                bfr[1][nt] = *reinterpret_cast<const bf16x8*>(  // next window
                    bRd + rs + (nt * 2 + 1) * 512);             // kstep 1
            __builtin_amdgcn_s_setprio(0);
            // final window's reloads read stale slot 0 data, never used
        }
    }

    // epilogue: 32x32 C/D layout col=lane&31, row=(reg&3)+8*(reg>>2)+4*lhi
    // (m74/m101-verified)
#pragma unroll
    for (int nt = 0; nt < 2; ++nt) {
        const int col = n0 + wn * 64 + nt * 32 + l31;
        const float bv = bias[col];
#pragma unroll
        for (int mt = 0; mt < 4; ++mt) {
            const int rowb = m0 + wm * 128 + mt * 32 + lhi * 4;
#pragma unroll
            for (int rg = 0; rg < 16; ++rg)
                C[(size_t)(rowb + (rg & 3) + 8 * (rg >> 2)) * N_ + col] =
                    acc[mt][nt][rg] + bv;
        }
    }
}

// ---------------------------------------------------------------------------
// Correctness-insurance fallback (only if ws too small; slow but exact)
// ---------------------------------------------------------------------------
__global__ __launch_bounds__(256) void naive_kernel(const float* __restrict__ x,
                                                    const float* __restrict__ cb,
                                                    const float* __restrict__ bias,
                                                    float* __restrict__ out) {
    const size_t t = (size_t)blockIdx.x * 256 + threadIdx.x;
    const int row = (int)(t / N_);
    const int col = (int)(t % N_);
    float s = bias[col];
    const float* xr = x + (size_t)row * K_;
    const int h = col * HA + HC3;
    for (int i = 0; i < K_; ++i) {
        float v = cb[(h + i * HB) & (CBOOK - 1)];
        s += xr[i] * (((col ^ i) & 1) ? -v : v);
    }
    out[t] = s;
}

extern "C" void kernel_launch(void* const* d_in, const int* in_sizes, int n_in,
                              void* d_out, int out_size, void* d_ws, size_t ws_size,
                              hipStream_t stream) {
    const float* x    = (const float*)d_in[0];
    const float* cb   = (const float*)d_in[1];
    const float* bias = (const float*)d_in[2];
    float* out = (float*)d_out;

    const size_t wBytes = (size_t)N_ * K_ * sizeof(unsigned short);  // 32 MiB
    const size_t xBytes = (size_t)M_ * K_ * sizeof(unsigned short);  // 64 MiB
    const size_t pBytes = (size_t)P2N * sizeof(unsigned short);      // 1 MiB

    if (ws_size >= wBytes + xBytes + pBytes) {
        unsigned short* Wf  = (unsigned short*)d_ws;
        unsigned short* xb  = (unsigned short*)((char*)d_ws + wBytes);
        unsigned short* P2p = (unsigned short*)((char*)d_ws + wBytes + xBytes);
        prep_p2<<<P2B, 256, 0, stream>>>(cb, P2p);
        prep_main<<<GENB + CONVB, 256, 0, stream>>>(x, P2p, Wf, xb);
        // grid x = 16 n-strips: XCD = linear%8 = x%8; each XCD's Wf slice is
        // 2 strips x 2MB = 4MB = its L2.  B stream stays L2-resident.
        gemm_kernel<<<dim3(N_ / BN, M_ / BM), 512, 0, stream>>>(xb, Wf, bias, out);
    } else {
        naive_kernel<<<(int)((size_t)M_ * N_ / 256), 256, 0, stream>>>(x, cb, bias, out);
    }
}